// Round 1
// baseline (7594.122 us; speedup 1.0000x reference)
//
#include <hip/hip_runtime.h>
#include <hip/hip_bf16.h>

// Problem constants (setup_inputs): T=512, B=64, H=1024, V=32000, C=32000, HID_NUM=2
#define T_DIM 512
#define B_DIM 64
#define H_DIM 1024
#define C_DIM 32000
#define W1_LD 6144            // w1 is (H, 6H) row-major
#define TH    (T_DIM * H_DIM) // 524288

typedef __attribute__((ext_vector_type(8))) short s16x8;  // 8 bf16 = 4 VGPRs (MFMA A/B frag)
typedef __attribute__((ext_vector_type(4))) float f32x4;  // MFMA C/D frag

// ---------- bf16 helpers ----------
__device__ __forceinline__ unsigned short bf_rne(float f) {
    union { float f; unsigned u; } v; v.f = f;
    unsigned u = v.u;
    return (unsigned short)((u + 0x7FFFu + ((u >> 16) & 1u)) >> 16);
}
__device__ __forceinline__ float bf2f(unsigned short s) {
    union { unsigned u; float f; } v; v.u = ((unsigned)s) << 16;
    return v.f;
}
__device__ __forceinline__ s16x8 pack_bf(f32x4 a, f32x4 b) {
    s16x8 o;
    o[0] = (short)bf_rne(a[0]); o[1] = (short)bf_rne(a[1]);
    o[2] = (short)bf_rne(a[2]); o[3] = (short)bf_rne(a[3]);
    o[4] = (short)bf_rne(b[0]); o[5] = (short)bf_rne(b[1]);
    o[6] = (short)bf_rne(b[2]); o[7] = (short)bf_rne(b[3]);
    return o;
}

// ---------- workspace layout (bytes) ----------
// xin bf16 [T*B][H]          : 67,108,864
// WxP  bf16 packed B-frags   :  2,097,152
// WhP  bf16 packed B-frags   :  2,097,152
// hbuf bf16 [2][B][H]        :    262,144
// barrier counters           :      1,024
#define OFF_XIN 0
#define OFF_WXP 67108864UL
#define OFF_WHP 69206016UL
#define OFF_H   71303168UL
#define OFF_CNT 71565312UL

// =====================================================================
// Kernel 1: pack Wx and Wh (fp32, column-strided in w1) into bf16 MFMA
// B-fragment layout: P[((ct*32 + kb)*64 + lane)*8 + j] = W[kb*32 + (lane>>4)*8 + j][ct*16 + (lane&15)]
// =====================================================================
__global__ void pack_w(const float* __restrict__ w1,
                       unsigned short* __restrict__ wxp,
                       unsigned short* __restrict__ whp) {
    unsigned f = blockIdx.x * 256 + threadIdx.x;   // < 1048576
    unsigned j  = f & 7u;
    unsigned l  = (f >> 3) & 63u;
    unsigned kb = (f >> 9) & 31u;
    unsigned ct = f >> 14;
    unsigned k = kb * 32u + ((l >> 4) * 8u) + j;
    unsigned c = ct * 16u + (l & 15u);
    wxp[f] = bf_rne(w1[(size_t)k * W1_LD + c]);          // Wx = w1[:, 0:H]
    whp[f] = bf_rne(w1[(size_t)k * W1_LD + 1024 + c]);   // Wh = w1[:, H:2H]
}

// =====================================================================
// Kernel 2: xin = gather(emb, x) @ Wx + b1[:H], output bf16 [T*B][H]
// Per-wave job: 64 rows x 64 cols (4x4 subtiles of 16x16x32 MFMA), K=1024
// =====================================================================
__global__ void gemm_xin(const int* __restrict__ x,
                         const float* __restrict__ emb,
                         const unsigned short* __restrict__ wxp,
                         const float* __restrict__ b1,
                         unsigned short* __restrict__ xin) {
    const int wave = threadIdx.x >> 6;
    const int lane = threadIdx.x & 63;
    const int quad = lane >> 4;
    const int n16  = lane & 15;
    const int id = blockIdx.x * 4 + wave;   // 0..8191
    const int mj = id >> 4;                 // 0..511  (64-row slab)
    const int nj = id & 15;                 // 0..15   (64-col slab)

    int idxv[4];
    #pragma unroll
    for (int i = 0; i < 4; ++i)
        idxv[i] = x[(size_t)(mj * 64 + i * 16 + n16)];

    float bias[4];
    #pragma unroll
    for (int n = 0; n < 4; ++n)
        bias[n] = b1[nj * 64 + n * 16 + n16];

    f32x4 acc[4][4];
    #pragma unroll
    for (int i = 0; i < 4; ++i)
        #pragma unroll
        for (int n = 0; n < 4; ++n)
            acc[i][n] = (f32x4){0.f, 0.f, 0.f, 0.f};

    for (int kb = 0; kb < 32; ++kb) {
        s16x8 a[4];
        #pragma unroll
        for (int i = 0; i < 4; ++i) {
            const float* ap = emb + (size_t)idxv[i] * H_DIM + kb * 32 + quad * 8;
            f32x4 lo = *(const f32x4*)ap;
            f32x4 hi = *(const f32x4*)(ap + 4);
            a[i] = pack_bf(lo, hi);
        }
        s16x8 b[4];
        #pragma unroll
        for (int n = 0; n < 4; ++n)
            b[n] = *(const s16x8*)(wxp + (size_t)((nj * 4 + n) * 32 + kb) * 512 + lane * 8);
        #pragma unroll
        for (int i = 0; i < 4; ++i)
            #pragma unroll
            for (int n = 0; n < 4; ++n)
                acc[i][n] = __builtin_amdgcn_mfma_f32_16x16x32_bf16(a[i], b[n], acc[i][n], 0, 0, 0);
    }

    #pragma unroll
    for (int i = 0; i < 4; ++i)
        #pragma unroll
        for (int n = 0; n < 4; ++n)
            #pragma unroll
            for (int r = 0; r < 4; ++r) {
                int row = mj * 64 + i * 16 + quad * 4 + r;
                int col = nj * 64 + n * 16 + n16;
                xin[(size_t)row * H_DIM + col] = bf_rne(acc[i][n][r] + bias[n]);
            }
}

// =====================================================================
// Kernel 3: the recurrence. 64 WGs x 256 thr; WG g: batch-group p=g&3
// (16 batches), col-group qg=g>>2 (64 cols; 1 wave = 16 cols).
// Wh B-frags pinned in VGPRs; per substep only h (32KB/wave) is re-read.
// Barrier only among the 16 WGs sharing a batch group.
// =====================================================================
__device__ __forceinline__ void group_barrier(unsigned* cnt, unsigned target) {
    __syncthreads();   // all waves' h stores retired (vmcnt 0) before arrival
    if (threadIdx.x == 0) {
        __hip_atomic_fetch_add(cnt, 1u, __ATOMIC_RELEASE, __HIP_MEMORY_SCOPE_AGENT);
        while (__hip_atomic_load(cnt, __ATOMIC_ACQUIRE, __HIP_MEMORY_SCOPE_AGENT) < target)
            __builtin_amdgcn_s_sleep(2);
    }
    __syncthreads();
}

__global__ __launch_bounds__(256, 1) void rnn_recur(
        const unsigned short* __restrict__ xin,   // [T*B][H] bf16
        const unsigned short* __restrict__ whp,   // packed B-frags
        unsigned short* __restrict__ hbuf,        // [2][B][H] bf16
        float* __restrict__ out,                  // [B][T*H] fp32
        unsigned* __restrict__ cnt) {             // 4 counters, 256B apart
    const int g    = blockIdx.x;
    const int p    = g & 3;        // batch group (16 batches)
    const int qg   = g >> 2;       // col group (64 cols)
    const int wave = threadIdx.x >> 6;
    const int lane = threadIdx.x & 63;
    const int quad = lane >> 4;
    const int n16  = lane & 15;
    const int ct   = qg * 4 + wave;       // 16-col tile id, 0..63
    const int c    = ct * 16 + n16;       // this lane's output column

    // Wh B-fragments for our 16 columns: resident in VGPRs for entire kernel
    s16x8 bfr[32];
    #pragma unroll
    for (int kb = 0; kb < 32; ++kb)
        bfr[kb] = *(const s16x8*)(whp + (size_t)(ct * 32 + kb) * 512 + lane * 8);

    unsigned* myc = cnt + p * 64;          // group-private counter (256B apart)
    unsigned target = 0;

    const int arow  = p * 16 + n16;        // row this lane LOADS (A frag: m = lane&15)
    const int orow0 = p * 16 + quad * 4;   // first row this lane OWNS (C/D: row = quad*4+r)

    float xf[4], val[4];

    // t = 0 : h0 = tanh(xin[0])
    #pragma unroll
    for (int r = 0; r < 4; ++r)
        xf[r] = bf2f(xin[(size_t)(orow0 + r) * H_DIM + c]);
    #pragma unroll
    for (int r = 0; r < 4; ++r) {
        val[r] = tanhf(xf[r]);
        hbuf[(size_t)(orow0 + r) * H_DIM + c] = bf_rne(val[r]);                   // parity 0
        out[(size_t)(orow0 + r) * TH + c] = val[r];
    }
    target += 16;
    group_barrier(myc, target);

    int s = 1;  // substep index; writes parity s&1, reads parity (s+1)&1
    for (int t = 1; t < T_DIM; ++t) {
        #pragma unroll
        for (int r = 0; r < 4; ++r)
            xf[r] = bf2f(xin[(size_t)(t * B_DIM + orow0 + r) * H_DIM + c]);
        #pragma unroll
        for (int it = 0; it < 2; ++it) {   // HID_NUM = 2
            const unsigned short* hr = hbuf + (size_t)((s + 1) & 1) * (B_DIM * H_DIM);
            unsigned short*       hw = hbuf + (size_t)(s & 1) * (B_DIM * H_DIM);
            const unsigned short* abase = hr + (size_t)arow * H_DIM + quad * 8;

            f32x4 acc0 = {0.f, 0.f, 0.f, 0.f};
            f32x4 acc1 = {0.f, 0.f, 0.f, 0.f};
            #pragma unroll
            for (int kb = 0; kb < 32; kb += 2) {
                s16x8 a0 = *(const s16x8*)(abase + kb * 32);
                s16x8 a1 = *(const s16x8*)(abase + kb * 32 + 32);
                acc0 = __builtin_amdgcn_mfma_f32_16x16x32_bf16(a0, bfr[kb],     acc0, 0, 0, 0);
                acc1 = __builtin_amdgcn_mfma_f32_16x16x32_bf16(a1, bfr[kb + 1], acc1, 0, 0, 0);
            }
            #pragma unroll
            for (int r = 0; r < 4; ++r) {
                val[r] = tanhf(xf[r] + acc0[r] + acc1[r]);
                hw[(size_t)(orow0 + r) * H_DIM + c] = bf_rne(val[r]);
            }
            if (it == 1) {
                #pragma unroll
                for (int r = 0; r < 4; ++r)
                    out[(size_t)(orow0 + r) * TH + (size_t)t * H_DIM + c] = val[r];
            }
            target += 16;
            group_barrier(myc, target);
            ++s;
        }
    }
    // total substeps = 1023 (odd) -> last write parity 0: h_last lives in hbuf[0]
}

// =====================================================================
// Kernel 4: y = h_last @ fc_w^T + fc_b   (64 x 32000, K=1024)
// fc_w is [C][H] row-major -> B frag (8 contiguous k per lane) is 2x float4
// =====================================================================
__global__ void gemm_y(const unsigned short* __restrict__ hlast,  // hbuf parity 0
                       const float* __restrict__ fc_w,
                       const float* __restrict__ fc_b,
                       float* __restrict__ y) {
    const int wave = threadIdx.x >> 6;
    const int lane = threadIdx.x & 63;
    const int quad = lane >> 4;
    const int n16  = lane & 15;
    const int id = blockIdx.x * 4 + wave;   // 0..1999
    const int n0 = id * 16;

    f32x4 acc[4];
    #pragma unroll
    for (int i = 0; i < 4; ++i) acc[i] = (f32x4){0.f, 0.f, 0.f, 0.f};

    for (int kb = 0; kb < 32; ++kb) {
        const float* bp = fc_w + (size_t)(n0 + n16) * H_DIM + kb * 32 + quad * 8;
        s16x8 b = pack_bf(*(const f32x4*)bp, *(const f32x4*)(bp + 4));
        #pragma unroll
        for (int i = 0; i < 4; ++i) {
            s16x8 a = *(const s16x8*)(hlast + (size_t)(i * 16 + n16) * H_DIM + kb * 32 + quad * 8);
            acc[i] = __builtin_amdgcn_mfma_f32_16x16x32_bf16(a, b, acc[i], 0, 0, 0);
        }
    }

    const int cc = n0 + n16;
    const float bias = fc_b[cc];
    #pragma unroll
    for (int i = 0; i < 4; ++i)
        #pragma unroll
        for (int r = 0; r < 4; ++r)
            y[(size_t)(i * 16 + quad * 4 + r) * C_DIM + cc] = acc[i][r] + bias;
}

// =====================================================================
extern "C" void kernel_launch(void* const* d_in, const int* in_sizes, int n_in,
                              void* d_out, int out_size, void* d_ws, size_t ws_size,
                              hipStream_t stream) {
    const int*   x    = (const int*)  d_in[0];
    const float* emb  = (const float*)d_in[1];
    const float* w1   = (const float*)d_in[2];
    const float* b1   = (const float*)d_in[3];
    const float* fc_w = (const float*)d_in[4];
    const float* fc_b = (const float*)d_in[5];

    char* ws = (char*)d_ws;
    unsigned short* xin  = (unsigned short*)(ws + OFF_XIN);
    unsigned short* wxp  = (unsigned short*)(ws + OFF_WXP);
    unsigned short* whp  = (unsigned short*)(ws + OFF_WHP);
    unsigned short* hbuf = (unsigned short*)(ws + OFF_H);
    unsigned*       cnt  = (unsigned*)(ws + OFF_CNT);

    float* y    = (float*)d_out;                       // [64][32000]
    float* outp = (float*)d_out + (size_t)B_DIM * C_DIM; // [64][T*H]

    hipMemsetAsync(ws + OFF_CNT, 0, 1024, stream);
    pack_w  <<<4096, 256, 0, stream>>>(w1, wxp, whp);
    gemm_xin<<<2048, 256, 0, stream>>>(x, emb, wxp, b1, xin);
    rnn_recur<<<64,  256, 0, stream>>>(xin, whp, hbuf, outp, cnt);
    gemm_y  <<<500,  256, 0, stream>>>(hbuf, fc_w, fc_b, y);
}

// Round 2
// 6780.975 us; speedup vs baseline: 1.1199x; 1.1199x over previous
//
#include <hip/hip_runtime.h>
#include <hip/hip_bf16.h>

// Problem constants (setup_inputs): T=512, B=64, H=1024, V=32000, C=32000, HID_NUM=2
#define T_DIM 512
#define B_DIM 64
#define H_DIM 1024
#define C_DIM 32000
#define W1_LD 6144            // w1 is (H, 6H) row-major
#define TH    (T_DIM * H_DIM) // 524288

typedef __attribute__((ext_vector_type(8))) short s16x8;  // 8 bf16 = 4 VGPRs (MFMA A/B frag)
typedef __attribute__((ext_vector_type(4))) float f32x4;  // MFMA C/D frag
typedef __attribute__((ext_vector_type(4))) unsigned short u16x4;

// ---------- bf16 helpers ----------
__device__ __forceinline__ unsigned short bf_rne(float f) {
    union { float f; unsigned u; } v; v.f = f;
    unsigned u = v.u;
    return (unsigned short)((u + 0x7FFFu + ((u >> 16) & 1u)) >> 16);
}
__device__ __forceinline__ float bf2f(unsigned short s) {
    union { unsigned u; float f; } v; v.u = ((unsigned)s) << 16;
    return v.f;
}
__device__ __forceinline__ s16x8 pack_bf(f32x4 a, f32x4 b) {
    s16x8 o;
    o[0] = (short)bf_rne(a[0]); o[1] = (short)bf_rne(a[1]);
    o[2] = (short)bf_rne(a[2]); o[3] = (short)bf_rne(a[3]);
    o[4] = (short)bf_rne(b[0]); o[5] = (short)bf_rne(b[1]);
    o[6] = (short)bf_rne(b[2]); o[7] = (short)bf_rne(b[3]);
    return o;
}

// ---------- workspace layout (bytes) ----------
// xin/hist bf16 [T][B][H]    : 67,108,864   (xin is consumed in-step and
//                                            overwritten with hist[t] = final h of step t)
// WxP  bf16 packed B-frags   :  2,097,152
// WhP  bf16 packed B-frags   :  2,097,152
// htmp bf16 [B][H]           :    131,072   (intermediate substep h)
// barrier counters           :      1,024
#define OFF_XIN 0
#define OFF_WXP 67108864UL
#define OFF_WHP 69206016UL
#define OFF_HT  71303168UL
#define OFF_CNT 71565312UL

// =====================================================================
// Kernel 1: pack Wx and Wh (fp32, column-strided in w1) into bf16 MFMA
// B-fragment layout: P[((ct*32 + kb)*64 + lane)*8 + j] = W[kb*32 + (lane>>4)*8 + j][ct*16 + (lane&15)]
// =====================================================================
__global__ void pack_w(const float* __restrict__ w1,
                       unsigned short* __restrict__ wxp,
                       unsigned short* __restrict__ whp) {
    unsigned f = blockIdx.x * 256 + threadIdx.x;   // < 1048576
    unsigned j  = f & 7u;
    unsigned l  = (f >> 3) & 63u;
    unsigned kb = (f >> 9) & 31u;
    unsigned ct = f >> 14;
    unsigned k = kb * 32u + ((l >> 4) * 8u) + j;
    unsigned c = ct * 16u + (l & 15u);
    wxp[f] = bf_rne(w1[(size_t)k * W1_LD + c]);          // Wx = w1[:, 0:H]
    whp[f] = bf_rne(w1[(size_t)k * W1_LD + 1024 + c]);   // Wh = w1[:, H:2H]
}

// =====================================================================
// Kernel 2: xin = gather(emb, x) @ Wx + b1[:H], output bf16 [T*B][H]
// Per-wave job: 64 rows x 64 cols (4x4 subtiles of 16x16x32 MFMA), K=1024
// =====================================================================
__global__ void gemm_xin(const int* __restrict__ x,
                         const float* __restrict__ emb,
                         const unsigned short* __restrict__ wxp,
                         const float* __restrict__ b1,
                         unsigned short* __restrict__ xin) {
    const int wave = threadIdx.x >> 6;
    const int lane = threadIdx.x & 63;
    const int quad = lane >> 4;
    const int n16  = lane & 15;
    const int id = blockIdx.x * 4 + wave;   // 0..8191
    const int mj = id >> 4;                 // 0..511  (64-row slab)
    const int nj = id & 15;                 // 0..15   (64-col slab)

    int idxv[4];
    #pragma unroll
    for (int i = 0; i < 4; ++i)
        idxv[i] = x[(size_t)(mj * 64 + i * 16 + n16)];

    float bias[4];
    #pragma unroll
    for (int n = 0; n < 4; ++n)
        bias[n] = b1[nj * 64 + n * 16 + n16];

    f32x4 acc[4][4];
    #pragma unroll
    for (int i = 0; i < 4; ++i)
        #pragma unroll
        for (int n = 0; n < 4; ++n)
            acc[i][n] = (f32x4){0.f, 0.f, 0.f, 0.f};

    for (int kb = 0; kb < 32; ++kb) {
        s16x8 a[4];
        #pragma unroll
        for (int i = 0; i < 4; ++i) {
            const float* ap = emb + (size_t)idxv[i] * H_DIM + kb * 32 + quad * 8;
            f32x4 lo = *(const f32x4*)ap;
            f32x4 hi = *(const f32x4*)(ap + 4);
            a[i] = pack_bf(lo, hi);
        }
        s16x8 b[4];
        #pragma unroll
        for (int n = 0; n < 4; ++n)
            b[n] = *(const s16x8*)(wxp + (size_t)((nj * 4 + n) * 32 + kb) * 512 + lane * 8);
        #pragma unroll
        for (int i = 0; i < 4; ++i)
            #pragma unroll
            for (int n = 0; n < 4; ++n)
                acc[i][n] = __builtin_amdgcn_mfma_f32_16x16x32_bf16(a[i], b[n], acc[i][n], 0, 0, 0);
    }

    #pragma unroll
    for (int i = 0; i < 4; ++i)
        #pragma unroll
        for (int n = 0; n < 4; ++n)
            #pragma unroll
            for (int r = 0; r < 4; ++r) {
                int row = mj * 64 + i * 16 + quad * 4 + r;
                int col = nj * 64 + n * 16 + n16;
                xin[(size_t)row * H_DIM + col] = bf_rne(acc[i][n][r] + bias[n]);
            }
}

// =====================================================================
// Kernel 3: the recurrence. 64 WGs x 256 thr; WG g: batch-group p=g&3
// (16 batches), col-group qg=g>>2 (64 cols; 1 wave = 16 cols).
// Wh B-frags pinned in VGPRs; per substep only h (32KB/wave) is re-read.
// Barrier only among the 16 WGs sharing a batch group.
// R2: relaxed polls + ONE acquire fence per barrier pass (no inv-per-poll);
//     no fp32 out writes in-loop — final h of step t overwrites xin[t] (bf16),
//     expanded to fp32 out by hist_to_out afterwards.
// =====================================================================
__device__ __forceinline__ void group_barrier(unsigned* cnt, unsigned target) {
    __syncthreads();   // all waves' h stores retired to L2 before arrival
    if (threadIdx.x == 0) {
        // release: wbl2 (flushes this XCD's dirty h lines to MALL) + add at MALL
        __hip_atomic_fetch_add(cnt, 1u, __ATOMIC_RELEASE, __HIP_MEMORY_SCOPE_AGENT);
        // spin with RELAXED loads (sc1 -> reads MALL directly, no cache inv)
        while (__hip_atomic_load(cnt, __ATOMIC_RELAXED, __HIP_MEMORY_SCOPE_AGENT) < target)
            __builtin_amdgcn_s_sleep(1);
        // one acquire fence: invalidate stale L1/L2 lines before h reloads
        __builtin_amdgcn_fence(__ATOMIC_ACQUIRE, "agent");
    }
    __syncthreads();
}

__global__ __launch_bounds__(256, 1) void rnn_recur(
        unsigned short* __restrict__ hist,        // [T][B][H] bf16: in = xin, out = h history
        const unsigned short* __restrict__ whp,   // packed B-frags
        unsigned short* __restrict__ htmp,        // [B][H] bf16 intermediate substep
        unsigned* __restrict__ cnt) {             // 4 counters, 256B apart
    const int g    = blockIdx.x;
    const int p    = g & 3;        // batch group (16 batches)
    const int qg   = g >> 2;       // col group (64 cols)
    const int wave = threadIdx.x >> 6;
    const int lane = threadIdx.x & 63;
    const int quad = lane >> 4;
    const int n16  = lane & 15;
    const int ct   = qg * 4 + wave;       // 16-col tile id, 0..63
    const int c    = ct * 16 + n16;       // this lane's output column

    // Wh B-fragments for our 16 columns: resident in VGPRs for entire kernel
    s16x8 bfr[32];
    #pragma unroll
    for (int kb = 0; kb < 32; ++kb)
        bfr[kb] = *(const s16x8*)(whp + (size_t)(ct * 32 + kb) * 512 + lane * 8);

    unsigned* myc = cnt + p * 64;          // group-private counter (256B apart)
    unsigned target = 0;

    const int arow  = p * 16 + n16;        // row this lane LOADS (A frag: m = lane&15)
    const int orow0 = p * 16 + quad * 4;   // first row this lane OWNS (C/D: row = quad*4+r)

    float xf[4], val[4];

    // t = 0 : h0 = tanh(xin[0]); overwrite xin[0] in place (per-lane same address)
    #pragma unroll
    for (int r = 0; r < 4; ++r)
        xf[r] = bf2f(hist[(size_t)(orow0 + r) * H_DIM + c]);
    #pragma unroll
    for (int r = 0; r < 4; ++r)
        hist[(size_t)(orow0 + r) * H_DIM + c] = bf_rne(tanhf(xf[r]));
    target += 16;
    group_barrier(myc, target);

    for (int t = 1; t < T_DIM; ++t) {
        unsigned short* xt = hist + (size_t)t * (B_DIM * H_DIM);
        #pragma unroll
        for (int r = 0; r < 4; ++r)
            xf[r] = bf2f(xt[(size_t)(orow0 + r) * H_DIM + c]);
        #pragma unroll
        for (int it = 0; it < 2; ++it) {   // HID_NUM = 2
            // it=0: read hist[t-1], write htmp ; it=1: read htmp, write hist[t]
            const unsigned short* hr = (it == 0)
                ? hist + (size_t)(t - 1) * (B_DIM * H_DIM) : htmp;
            unsigned short* hw = (it == 0) ? htmp : xt;
            const unsigned short* abase = hr + (size_t)arow * H_DIM + quad * 8;

            f32x4 acc0 = {0.f, 0.f, 0.f, 0.f};
            f32x4 acc1 = {0.f, 0.f, 0.f, 0.f};
            #pragma unroll
            for (int kb = 0; kb < 32; kb += 2) {
                s16x8 a0 = *(const s16x8*)(abase + kb * 32);
                s16x8 a1 = *(const s16x8*)(abase + kb * 32 + 32);
                acc0 = __builtin_amdgcn_mfma_f32_16x16x32_bf16(a0, bfr[kb],     acc0, 0, 0, 0);
                acc1 = __builtin_amdgcn_mfma_f32_16x16x32_bf16(a1, bfr[kb + 1], acc1, 0, 0, 0);
            }
            #pragma unroll
            for (int r = 0; r < 4; ++r) {
                val[r] = tanhf(xf[r] + acc0[r] + acc1[r]);
                hw[(size_t)(orow0 + r) * H_DIM + c] = bf_rne(val[r]);
            }
            target += 16;
            group_barrier(myc, target);
        }
    }
    // h_last = hist[T-1]
}

// =====================================================================
// Kernel 4: expand h history bf16 [T][B][H] -> out fp32 [B][T*H]
// =====================================================================
__global__ void hist_to_out(const unsigned short* __restrict__ hist,
                            float* __restrict__ out) {
    size_t i = ((size_t)blockIdx.x * 256 + threadIdx.x) * 4;  // flat [t][b][h]
    unsigned h = (unsigned)(i & 1023u);
    unsigned b = (unsigned)((i >> 10) & 63u);
    unsigned t = (unsigned)(i >> 16);
    u16x4 v = *(const u16x4*)(hist + i);
    f32x4 o;
    o[0] = bf2f(v[0]); o[1] = bf2f(v[1]); o[2] = bf2f(v[2]); o[3] = bf2f(v[3]);
    *(f32x4*)(out + (size_t)b * TH + (size_t)t * H_DIM + h) = o;
}

// =====================================================================
// Kernel 5: y = h_last @ fc_w^T + fc_b   (64 x 32000, K=1024)
// fc_w is [C][H] row-major -> B frag (8 contiguous k per lane) is 2x float4
// =====================================================================
__global__ void gemm_y(const unsigned short* __restrict__ hlast,  // hist[T-1]
                       const float* __restrict__ fc_w,
                       const float* __restrict__ fc_b,
                       float* __restrict__ y) {
    const int wave = threadIdx.x >> 6;
    const int lane = threadIdx.x & 63;
    const int quad = lane >> 4;
    const int n16  = lane & 15;
    const int id = blockIdx.x * 4 + wave;   // 0..1999
    const int n0 = id * 16;

    f32x4 acc[4];
    #pragma unroll
    for (int i = 0; i < 4; ++i) acc[i] = (f32x4){0.f, 0.f, 0.f, 0.f};

    for (int kb = 0; kb < 32; ++kb) {
        const float* bp = fc_w + (size_t)(n0 + n16) * H_DIM + kb * 32 + quad * 8;
        s16x8 b = pack_bf(*(const f32x4*)bp, *(const f32x4*)(bp + 4));
        #pragma unroll
        for (int i = 0; i < 4; ++i) {
            s16x8 a = *(const s16x8*)(hlast + (size_t)(i * 16 + n16) * H_DIM + kb * 32 + quad * 8);
            acc[i] = __builtin_amdgcn_mfma_f32_16x16x32_bf16(a, b, acc[i], 0, 0, 0);
        }
    }

    const int cc = n0 + n16;
    const float bias = fc_b[cc];
    #pragma unroll
    for (int i = 0; i < 4; ++i)
        #pragma unroll
        for (int r = 0; r < 4; ++r)
            y[(size_t)(i * 16 + quad * 4 + r) * C_DIM + cc] = acc[i][r] + bias;
}

// =====================================================================
extern "C" void kernel_launch(void* const* d_in, const int* in_sizes, int n_in,
                              void* d_out, int out_size, void* d_ws, size_t ws_size,
                              hipStream_t stream) {
    const int*   x    = (const int*)  d_in[0];
    const float* emb  = (const float*)d_in[1];
    const float* w1   = (const float*)d_in[2];
    const float* b1   = (const float*)d_in[3];
    const float* fc_w = (const float*)d_in[4];
    const float* fc_b = (const float*)d_in[5];

    char* ws = (char*)d_ws;
    unsigned short* xin  = (unsigned short*)(ws + OFF_XIN);   // becomes hist
    unsigned short* wxp  = (unsigned short*)(ws + OFF_WXP);
    unsigned short* whp  = (unsigned short*)(ws + OFF_WHP);
    unsigned short* htmp = (unsigned short*)(ws + OFF_HT);
    unsigned*       cnt  = (unsigned*)(ws + OFF_CNT);

    float* y    = (float*)d_out;                         // [64][32000]
    float* outp = (float*)d_out + (size_t)B_DIM * C_DIM; // [64][T*H]

    hipMemsetAsync(ws + OFF_CNT, 0, 1024, stream);
    pack_w     <<<4096, 256, 0, stream>>>(w1, wxp, whp);
    gemm_xin   <<<2048, 256, 0, stream>>>(x, emb, wxp, b1, xin);
    rnn_recur  <<<64,   256, 0, stream>>>(xin, whp, htmp, cnt);
    hist_to_out<<<32768, 256, 0, stream>>>(xin, outp);
    gemm_y     <<<500,  256, 0, stream>>>(xin + (size_t)(T_DIM - 1) * B_DIM * H_DIM,
                                          fc_w, fc_b, y);
}